// Round 2
// baseline (255.380 us; speedup 1.0000x reference)
//
#include <hip/hip_runtime.h>

typedef unsigned int u32;
typedef unsigned short u16;
typedef __attribute__((ext_vector_type(4))) float f32x4;
typedef __attribute__((ext_vector_type(8))) __bf16 bf16x8;
typedef __attribute__((ext_vector_type(4))) u32 u32x4;

// fp32 -> bf16 round-to-nearest-even
__device__ __forceinline__ u32 f2bf(float f) {
    u32 u = __builtin_bit_cast(u32, f);
    return (u + 0x7fffu + ((u >> 16) & 1u)) >> 16;
}
// fp32 -> bf16 round-half-up (2 VALU ops; <=0.5ulp, used only on hidden acts)
__device__ __forceinline__ u32 f2bf_fast(float f) {
    u32 u = __builtin_bit_cast(u32, f);
    return (u + 0x8000u) >> 16;
}
__device__ __forceinline__ u32 pk2(float lo, float hi) {
    return f2bf(lo) | (f2bf(hi) << 16);
}
__device__ __forceinline__ float bf2f(u16 v) {
    return __builtin_bit_cast(float, ((u32)v) << 16);
}

// 16 rows x 136 bf16 (pad +8 => 2-way-max LDS bank aliasing, free per m136)
union LdsTile {
    u16 h[16 * 136];
    u32x4 v[16 * 17];
};

// ---------------------------------------------------------------------------
// Kernel 0: x_nbr (f32) -> bf16 table in ws. Halves gather bytes and removes
// all pack VALU from the edge kernel's staging path.
// ---------------------------------------------------------------------------
__global__ void bf16_cast_kernel(const float* __restrict__ x,
                                 u32x4* __restrict__ y, int n8)
{
    const int i = blockIdx.x * blockDim.x + threadIdx.x;
    if (i >= n8) return;
    const float4* xp = (const float4*)x + (size_t)i * 2;
    const float4 a = xp[0], b = xp[1];
    u32x4 p;
    p[0] = pk2(a.x, a.y); p[1] = pk2(a.z, a.w);
    p[2] = pk2(b.x, b.y); p[3] = pk2(b.z, b.w);
    y[i] = p;
}

// ---------------------------------------------------------------------------
// Kernel 1 (fused): per 16-agent tile:
//   proj  = x_agent . W1[128:] + b1          (bf16, to ws)
//   own   = x_agent . Wa + ba                -> out[a][256..263]
//   zero-fill out[a][128..255]  (pad slots 16..31 never touched by edges)
// ---------------------------------------------------------------------------
__global__ __launch_bounds__(256, 2)
void agent_kernel(const float* __restrict__ x_agent,
                  const float* __restrict__ W1,
                  const float* __restrict__ b1,
                  const float* __restrict__ Wa,
                  const float* __restrict__ ba,
                  u16* __restrict__ proj,
                  float* __restrict__ out, int n_agents)
{
    __shared__ LdsTile Abuf[4];
    const int wid = threadIdx.x >> 6;
    const int l   = threadIdx.x & 63;
    const int n   = l & 15;
    const int q   = l >> 4;

    // W1 high-half fragments (k = 128..255): 128 VGPRs
    u32x4 wf[8][4];
#pragma unroll
    for (int nt = 0; nt < 8; ++nt) {
        const int col = nt * 16 + n;
#pragma unroll
        for (int kk = 0; kk < 4; ++kk) {
            u32x4 w;
#pragma unroll
            for (int jp = 0; jp < 4; ++jp) {
                const int k = 128 + kk * 32 + q * 8 + jp * 2;
                w[jp] = pk2(W1[(size_t)k * 128 + col], W1[(size_t)(k + 1) * 128 + col]);
            }
            wf[nt][kk] = w;
        }
    }
    // Wa fragments, cols padded 8 -> 16 with zeros
    u32x4 waf[4];
#pragma unroll
    for (int kk = 0; kk < 4; ++kk) {
        u32x4 w;
#pragma unroll
        for (int jp = 0; jp < 4; ++jp) {
            const int k = kk * 32 + q * 8 + jp * 2;
            const float f0 = (n < 8) ? Wa[(size_t)k * 8 + n] : 0.f;
            const float f1 = (n < 8) ? Wa[(size_t)(k + 1) * 8 + n] : 0.f;
            w[jp] = pk2(f0, f1);
        }
        waf[kk] = w;
    }
    float b1v[8];
#pragma unroll
    for (int nt = 0; nt < 8; ++nt) b1v[nt] = b1[nt * 16 + n];
    const float bav = (n < 8) ? ba[n] : 0.f;

    const int n_tiles = n_agents >> 4;
    const int gw = blockIdx.x * 4 + wid;
    const int stride = gridDim.x * 4;
    const f32x4 zero = {0.f, 0.f, 0.f, 0.f};

    for (int t = gw; t < n_tiles; t += stride) {
        const int a0 = t * 16;
#pragma unroll
        for (int it = 0; it < 4; ++it) {
            const int m = it * 4 + q;
            const float* bp = x_agent + (size_t)(a0 + m) * 128 + n * 8;
            const float4 v0 = *(const float4*)bp;
            const float4 v1 = *(const float4*)(bp + 4);
            u32x4 pkv;
            pkv[0] = pk2(v0.x, v0.y); pkv[1] = pk2(v0.z, v0.w);
            pkv[2] = pk2(v1.x, v1.y); pkv[3] = pk2(v1.z, v1.w);
            Abuf[wid].v[m * 17 + n] = pkv;
        }
        f32x4 acc[8];
#pragma unroll
        for (int nt = 0; nt < 8; ++nt) acc[nt] = zero;
        f32x4 acca = zero;
#pragma unroll
        for (int kk = 0; kk < 4; ++kk) {
            const u32x4 a = Abuf[wid].v[n * 17 + kk * 4 + q];
#pragma unroll
            for (int nt = 0; nt < 8; ++nt)
                acc[nt] = __builtin_amdgcn_mfma_f32_16x16x32_bf16(
                    __builtin_bit_cast(bf16x8, a),
                    __builtin_bit_cast(bf16x8, wf[nt][kk]), acc[nt], 0, 0, 0);
            acca = __builtin_amdgcn_mfma_f32_16x16x32_bf16(
                __builtin_bit_cast(bf16x8, a),
                __builtin_bit_cast(bf16x8, waf[kk]), acca, 0, 0, 0);
        }
        // proj store (pre-relu partial + b1), bf16
#pragma unroll
        for (int nt = 0; nt < 8; ++nt) {
#pragma unroll
            for (int r = 0; r < 4; ++r) {
                const int m = q * 4 + r;
                proj[(size_t)(a0 + m) * 128 + nt * 16 + n] =
                    (u16)f2bf(acc[nt][r] + b1v[nt]);
            }
        }
        // zero-fill out cols [128,256): lane covers cols 128+n*8..+7 of 4 rows
        const float4 z = {0.f, 0.f, 0.f, 0.f};
#pragma unroll
        for (int it = 0; it < 4; ++it) {
            const int m = it * 4 + q;
            float4* zp = (float4*)(out + (size_t)(a0 + m) * 264 + 128 + n * 8);
            zp[0] = z; zp[1] = z;
        }
        // own score -> cols [256,264)
#pragma unroll
        for (int r = 0; r < 4; ++r) {
            const int m = q * 4 + r;
            if (n < 8) out[(size_t)(a0 + m) * 264 + 256 + n] = acca[r] + bav;
        }
    }
}

// ---------------------------------------------------------------------------
// Kernel 2: per-edge MLP, one wave per 16-edge tile (== one dst agent by the
// fixed graph layout: edge_dst = repeat(arange(N),16)). Software-pipelined:
// indices 2 tiles ahead, gathers + proj row 1 tile ahead.
// ---------------------------------------------------------------------------
__global__ __launch_bounds__(256, 2)
void edge_mlp_kernel(const u16* __restrict__ xnb,     // bf16 x_nbr table
                     const u16* __restrict__ proj,
                     const float* __restrict__ W1,
                     const float* __restrict__ W2,
                     const float* __restrict__ b2,
                     const int* __restrict__ edge_src,
                     const int* __restrict__ edge_dst,
                     const int* __restrict__ edge_slot,
                     float* __restrict__ out, int n_tiles)
{
    __shared__ LdsTile Abuf[4];
    __shared__ LdsTile Hbuf[4];
    const int wid = threadIdx.x >> 6;
    const int l   = threadIdx.x & 63;
    const int n   = l & 15;
    const int q   = l >> 4;

    // W1 low-half fragments (k = 0..127): 128 VGPRs
    u32x4 wf[8][4];
#pragma unroll
    for (int nt = 0; nt < 8; ++nt) {
        const int col = nt * 16 + n;
#pragma unroll
        for (int kk = 0; kk < 4; ++kk) {
            u32x4 w;
#pragma unroll
            for (int jp = 0; jp < 4; ++jp) {
                const int k = kk * 32 + q * 8 + jp * 2;
                w[jp] = pk2(W1[(size_t)k * 128 + col], W1[(size_t)(k + 1) * 128 + col]);
            }
            wf[nt][kk] = w;
        }
    }
    // W2 fragments (N padded 8->16)
    u32x4 w2f[4];
#pragma unroll
    for (int kk = 0; kk < 4; ++kk) {
        u32x4 w;
#pragma unroll
        for (int jp = 0; jp < 4; ++jp) {
            const int k = kk * 32 + q * 8 + jp * 2;
            const float f0 = (n < 8) ? W2[(size_t)k * 8 + n] : 0.f;
            const float f1 = (n < 8) ? W2[(size_t)(k + 1) * 8 + n] : 0.f;
            w[jp] = pk2(f0, f1);
        }
        w2f[kk] = w;
    }
    const float b2v = (n < 8) ? b2[n] : 0.f;

    const int stride = gridDim.x * 4;
    int t = blockIdx.x * 4 + wid;
    if (t >= n_tiles) return;

    // ---- pipeline prologue ----
    int srcA = 0, slotA = 0;
    if (l < 16) { srcA = edge_src[t * 16 + l]; slotA = edge_slot[t * 16 + l]; }
    int dstA = edge_dst[t * 16];                    // uniform within tile

    int t1 = (t + stride < n_tiles) ? t + stride : t;
    int srcB = 0, slotB = 0;
    if (l < 16) { srcB = edge_src[t1 * 16 + l]; slotB = edge_slot[t1 * 16 + l]; }
    int dstB = edge_dst[t1 * 16];

    u32x4 pf[4];                                    // gathered rows, tile t
#pragma unroll
    for (int it = 0; it < 4; ++it) {
        const int s = __shfl(srcA, it * 4 + q);
        pf[it] = *(const u32x4*)(xnb + (size_t)s * 128 + n * 8);
    }
    float pv[8];                                    // proj row, tile t
#pragma unroll
    for (int nt = 0; nt < 8; ++nt)
        pv[nt] = bf2f(proj[(size_t)dstA * 128 + nt * 16 + n]);

    const f32x4 zero = {0.f, 0.f, 0.f, 0.f};

    while (true) {
        // stage tile t into LDS
#pragma unroll
        for (int it = 0; it < 4; ++it)
            Abuf[wid].v[(it * 4 + q) * 17 + n] = pf[it];

        const bool last = (t + stride >= n_tiles);

        // issue prefetches for tile t1 (indices already resident)
#pragma unroll
        for (int it = 0; it < 4; ++it) {
            const int s = __shfl(srcB, it * 4 + q);
            pf[it] = *(const u32x4*)(xnb + (size_t)s * 128 + n * 8);
        }
        float pvn[8];
#pragma unroll
        for (int nt = 0; nt < 8; ++nt)
            pvn[nt] = bf2f(proj[(size_t)dstB * 128 + nt * 16 + n]);
        // indices for t2
        const int t2 = (t1 + stride < n_tiles) ? t1 + stride : t1;
        int srcC = 0, slotC = 0;
        if (l < 16) { srcC = edge_src[t2 * 16 + l]; slotC = edge_slot[t2 * 16 + l]; }
        const int dstC = edge_dst[t2 * 16];

        // layer 1: K=128
        f32x4 acc[8];
#pragma unroll
        for (int nt = 0; nt < 8; ++nt) acc[nt] = zero;
#pragma unroll
        for (int kk = 0; kk < 4; ++kk) {
            const u32x4 a = Abuf[wid].v[n * 17 + kk * 4 + q];
#pragma unroll
            for (int nt = 0; nt < 8; ++nt)
                acc[nt] = __builtin_amdgcn_mfma_f32_16x16x32_bf16(
                    __builtin_bit_cast(bf16x8, a),
                    __builtin_bit_cast(bf16x8, wf[nt][kk]), acc[nt], 0, 0, 0);
        }
        // epilogue: + proj[dst], relu, hidden -> LDS (bf16)
#pragma unroll
        for (int nt = 0; nt < 8; ++nt) {
#pragma unroll
            for (int r = 0; r < 4; ++r) {
                const float hv = fmaxf(acc[nt][r] + pv[nt], 0.f);
                Hbuf[wid].h[(q * 4 + r) * 136 + nt * 16 + n] = (u16)f2bf_fast(hv);
            }
        }
        // layer 2
        f32x4 acc2 = zero;
#pragma unroll
        for (int kk = 0; kk < 4; ++kk) {
            const u32x4 a2 = Hbuf[wid].v[n * 17 + kk * 4 + q];
            acc2 = __builtin_amdgcn_mfma_f32_16x16x32_bf16(
                __builtin_bit_cast(bf16x8, a2),
                __builtin_bit_cast(bf16x8, w2f[kk]), acc2, 0, 0, 0);
        }
        // dense-per-agent store
        float* orow = out + (size_t)dstA * 264;
#pragma unroll
        for (int r = 0; r < 4; ++r) {
            const int m  = q * 4 + r;
            const int sl = __shfl(slotA, m);
            if (n < 8) orow[sl * 8 + n] = acc2[r] + b2v;
        }

        if (last) break;
        t = t1; t1 = t2;
        srcA = srcB; slotA = slotB; dstA = dstB;
        srcB = srcC; slotB = slotC; dstB = dstC;
#pragma unroll
        for (int nt = 0; nt < 8; ++nt) pv[nt] = pvn[nt];
    }
}

extern "C" void kernel_launch(void* const* d_in, const int* in_sizes, int n_in,
                              void* d_out, int out_size, void* d_ws, size_t ws_size,
                              hipStream_t stream)
{
    const float* x_nbr   = (const float*)d_in[0];
    const float* x_agent = (const float*)d_in[1];
    const float* W1      = (const float*)d_in[2];
    const float* b1      = (const float*)d_in[3];
    const float* W2      = (const float*)d_in[4];
    const float* b2      = (const float*)d_in[5];
    const float* Wa      = (const float*)d_in[6];
    const float* ba      = (const float*)d_in[7];
    const int* edge_src  = (const int*)d_in[8];
    const int* edge_dst  = (const int*)d_in[9];
    const int* edge_slot = (const int*)d_in[10];

    const int E        = in_sizes[8];
    const int n_nbr    = in_sizes[0] / 128;
    const int n_agents = in_sizes[1] / 128;
    const int n_tiles  = E / 16;

    // ws layout: proj (n_agents*128 bf16 = 12.8 MB) | xnb (n_nbr*128 bf16 = 12.8 MB)
    u16* proj = (u16*)d_ws;
    u16* xnb  = (u16*)d_ws + (size_t)n_agents * 128;

    const int n8 = n_nbr * 16;  // groups of 8 floats
    bf16_cast_kernel<<<dim3((n8 + 255) / 256), dim3(256), 0, stream>>>(
        x_nbr, (u32x4*)xnb, n8);
    agent_kernel<<<dim3(256), dim3(256), 0, stream>>>(
        x_agent, W1, b1, Wa, ba, proj, (float*)d_out, n_agents);
    edge_mlp_kernel<<<dim3(1024), dim3(256), 0, stream>>>(
        xnb, proj, W1, W2, b2, edge_src, edge_dst, edge_slot,
        (float*)d_out, n_tiles);
}

// Round 3
// 175.224 us; speedup vs baseline: 1.4575x; 1.4575x over previous
//
#include <hip/hip_runtime.h>

typedef unsigned int u32;
typedef unsigned short u16;
typedef __attribute__((ext_vector_type(4))) float f32x4;
typedef __attribute__((ext_vector_type(8))) __bf16 bf16x8;
typedef __attribute__((ext_vector_type(4))) u32 u32x4;

// fp32 -> bf16 round-to-nearest-even
__device__ __forceinline__ u32 f2bf(float f) {
    u32 u = __builtin_bit_cast(u32, f);
    return (u + 0x7fffu + ((u >> 16) & 1u)) >> 16;
}
// fp32 -> bf16 round-half-up (cheaper; only on hidden activations)
__device__ __forceinline__ u32 f2bf_fast(float f) {
    u32 u = __builtin_bit_cast(u32, f);
    return (u + 0x8000u) >> 16;
}
__device__ __forceinline__ u32 pk2(float lo, float hi) {
    return f2bf(lo) | (f2bf(hi) << 16);
}
// unpack bf16 pair from u32
__device__ __forceinline__ float bflo(u32 a) { return __builtin_bit_cast(float, a << 16); }
__device__ __forceinline__ float bfhi(u32 a) { return __builtin_bit_cast(float, a & 0xffff0000u); }

// 16 rows x 136 bf16 (+8 pad: 2-way-max bank aliasing = free per m136)
union LdsTile {
    u16 h[16 * 136];
    u32x4 v[16 * 17];
};

// ---------------------------------------------------------------------------
// Precompute kernel. Key identity: relu comes AFTER the edge sum, so layer 1
// factors per-node:  hidden = relu(np[src] + ap[dst])
//   blocks [0, nbr_blocks):      np[s] = x_nbr[s]  . W1[0:128]        (bf16)
//   blocks [nbr_blocks, grid):   ap[a] = x_agent[a]. W1[128:256] + b1 (bf16)
//                                own   = x_agent . Wa + ba -> out[256..263]
//                                zero-fill out[128..255]
// 16x savings vs computing layer 1 per edge (800k rows -> 2x 50k rows).
// ---------------------------------------------------------------------------
__global__ __launch_bounds__(256, 2)
void precompute_kernel(const float* __restrict__ x_nbr,
                       const float* __restrict__ x_agent,
                       const float* __restrict__ W1,
                       const float* __restrict__ b1,
                       const float* __restrict__ Wa,
                       const float* __restrict__ ba,
                       u16* __restrict__ np, u16* __restrict__ ap,
                       float* __restrict__ out,
                       int n_nodes, int n_agents, int nbr_blocks)
{
    __shared__ LdsTile Abuf[4];
    const int wid = threadIdx.x >> 6;
    const int l   = threadIdx.x & 63;
    const int n   = l & 15;
    const int q   = l >> 4;
    const bool is_nbr = (int)blockIdx.x < nbr_blocks;

    // W1 half fragments: rows [0,128) for nbr part, [128,256) for agent part
    const float* Wb = W1 + (is_nbr ? 0 : 128 * 128);
    u32x4 wf[8][4];
#pragma unroll
    for (int nt = 0; nt < 8; ++nt) {
        const int col = nt * 16 + n;
#pragma unroll
        for (int kk = 0; kk < 4; ++kk) {
            u32x4 w;
#pragma unroll
            for (int jp = 0; jp < 4; ++jp) {
                const int k = kk * 32 + q * 8 + jp * 2;
                w[jp] = pk2(Wb[(size_t)k * 128 + col], Wb[(size_t)(k + 1) * 128 + col]);
            }
            wf[nt][kk] = w;
        }
    }
    const f32x4 zero = {0.f, 0.f, 0.f, 0.f};

    if (is_nbr) {
        const int n_tiles = n_nodes >> 4;
        const int gw = blockIdx.x * 4 + wid;
        const int stride = nbr_blocks * 4;
        for (int t = gw; t < n_tiles; t += stride) {
            const int a0 = t * 16;
#pragma unroll
            for (int it = 0; it < 4; ++it) {
                const int m = it * 4 + q;
                const float* bp = x_nbr + (size_t)(a0 + m) * 128 + n * 8;
                const float4 v0 = *(const float4*)bp;
                const float4 v1 = *(const float4*)(bp + 4);
                u32x4 pkv;
                pkv[0] = pk2(v0.x, v0.y); pkv[1] = pk2(v0.z, v0.w);
                pkv[2] = pk2(v1.x, v1.y); pkv[3] = pk2(v1.z, v1.w);
                Abuf[wid].v[m * 17 + n] = pkv;
            }
            f32x4 acc[8];
#pragma unroll
            for (int nt = 0; nt < 8; ++nt) acc[nt] = zero;
#pragma unroll
            for (int kk = 0; kk < 4; ++kk) {
                const u32x4 a = Abuf[wid].v[n * 17 + kk * 4 + q];
#pragma unroll
                for (int nt = 0; nt < 8; ++nt)
                    acc[nt] = __builtin_amdgcn_mfma_f32_16x16x32_bf16(
                        __builtin_bit_cast(bf16x8, a),
                        __builtin_bit_cast(bf16x8, wf[nt][kk]), acc[nt], 0, 0, 0);
            }
#pragma unroll
            for (int nt = 0; nt < 8; ++nt)
#pragma unroll
                for (int r = 0; r < 4; ++r)
                    np[(size_t)(a0 + q * 4 + r) * 128 + nt * 16 + n] =
                        (u16)f2bf(acc[nt][r]);
        }
    } else {
        // agent part: ap + own score + zero-fill
        u32x4 waf[4];
#pragma unroll
        for (int kk = 0; kk < 4; ++kk) {
            u32x4 w;
#pragma unroll
            for (int jp = 0; jp < 4; ++jp) {
                const int k = kk * 32 + q * 8 + jp * 2;
                const float f0 = (n < 8) ? Wa[(size_t)k * 8 + n] : 0.f;
                const float f1 = (n < 8) ? Wa[(size_t)(k + 1) * 8 + n] : 0.f;
                w[jp] = pk2(f0, f1);
            }
            waf[kk] = w;
        }
        float b1v[8];
#pragma unroll
        for (int nt = 0; nt < 8; ++nt) b1v[nt] = b1[nt * 16 + n];
        const float bav = (n < 8) ? ba[n] : 0.f;

        const int n_tiles = n_agents >> 4;
        const int agent_blocks = gridDim.x - nbr_blocks;
        const int gw = (blockIdx.x - nbr_blocks) * 4 + wid;
        const int stride = agent_blocks * 4;
        for (int t = gw; t < n_tiles; t += stride) {
            const int a0 = t * 16;
#pragma unroll
            for (int it = 0; it < 4; ++it) {
                const int m = it * 4 + q;
                const float* bp = x_agent + (size_t)(a0 + m) * 128 + n * 8;
                const float4 v0 = *(const float4*)bp;
                const float4 v1 = *(const float4*)(bp + 4);
                u32x4 pkv;
                pkv[0] = pk2(v0.x, v0.y); pkv[1] = pk2(v0.z, v0.w);
                pkv[2] = pk2(v1.x, v1.y); pkv[3] = pk2(v1.z, v1.w);
                Abuf[wid].v[m * 17 + n] = pkv;
            }
            f32x4 acc[8];
#pragma unroll
            for (int nt = 0; nt < 8; ++nt) acc[nt] = zero;
            f32x4 acca = zero;
#pragma unroll
            for (int kk = 0; kk < 4; ++kk) {
                const u32x4 a = Abuf[wid].v[n * 17 + kk * 4 + q];
#pragma unroll
                for (int nt = 0; nt < 8; ++nt)
                    acc[nt] = __builtin_amdgcn_mfma_f32_16x16x32_bf16(
                        __builtin_bit_cast(bf16x8, a),
                        __builtin_bit_cast(bf16x8, wf[nt][kk]), acc[nt], 0, 0, 0);
                acca = __builtin_amdgcn_mfma_f32_16x16x32_bf16(
                    __builtin_bit_cast(bf16x8, a),
                    __builtin_bit_cast(bf16x8, waf[kk]), acca, 0, 0, 0);
            }
#pragma unroll
            for (int nt = 0; nt < 8; ++nt)
#pragma unroll
                for (int r = 0; r < 4; ++r)
                    ap[(size_t)(a0 + q * 4 + r) * 128 + nt * 16 + n] =
                        (u16)f2bf(acc[nt][r] + b1v[nt]);
            const float4 z = {0.f, 0.f, 0.f, 0.f};
#pragma unroll
            for (int it = 0; it < 4; ++it) {
                const int m = it * 4 + q;
                float4* zp = (float4*)(out + (size_t)(a0 + m) * 264 + 128 + n * 8);
                zp[0] = z; zp[1] = z;
            }
#pragma unroll
            for (int r = 0; r < 4; ++r) {
                const int m = q * 4 + r;
                if (n < 8) out[(size_t)(a0 + m) * 264 + 256 + n] = acca[r] + bav;
            }
        }
    }
}

// ---------------------------------------------------------------------------
// Edge kernel: per 16-edge tile (one dst agent): gather np[src] rows DIRECTLY
// in MFMA A-fragment layout (lane(n,q), kk: np[src_n][kk*32+q*8..+7]), add
// ap[dst], relu, repack bf16, 4 MFMAs vs W2, store. No LDS, no W1, no
// barriers; ping-pong prefetch, ~16 waves/CU.
// ---------------------------------------------------------------------------
#define EDGE_STEP(cnp, cap, csrc, cslot, cdst, nnp, nap, nsrc, nslot, ndst)      \
  {                                                                              \
    const int t2 = (t1 + stride < n_tiles) ? t1 + stride : t1;                   \
    _Pragma("unroll") for (int kk = 0; kk < 4; ++kk) {                           \
        const int s = __shfl(nsrc, n);                                           \
        nnp[kk] = *(const u32x4*)(np + (size_t)s * 128 + kk * 32 + q * 8);       \
    }                                                                            \
    _Pragma("unroll") for (int kk = 0; kk < 4; ++kk)                             \
        nap[kk] = *(const u32x4*)(ap + (size_t)ndst * 128 + kk * 32 + q * 8);    \
    const int sdst = cdst;                                                       \
    const int sslot = cslot;                                                     \
    const bool done = (t1 == t);                                                 \
    if (!done) {                                                                 \
        if (l < 16) { csrc = edge_src[t2 * 16 + l]; cslot = edge_slot[t2 * 16 + l]; } \
        cdst = edge_dst[t2 * 16];                                                \
    }                                                                            \
    f32x4 acc2 = {0.f, 0.f, 0.f, 0.f};                                           \
    _Pragma("unroll") for (int kk = 0; kk < 4; ++kk) {                           \
        u32x4 hf;                                                                \
        _Pragma("unroll") for (int j = 0; j < 4; ++j) {                          \
            const u32 av = cnp[kk][j], bv = cap[kk][j];                          \
            const float lo = fmaxf(bflo(av) + bflo(bv), 0.f);                    \
            const float hi = fmaxf(bfhi(av) + bfhi(bv), 0.f);                    \
            hf[j] = f2bf_fast(lo) | (f2bf_fast(hi) << 16);                       \
        }                                                                        \
        acc2 = __builtin_amdgcn_mfma_f32_16x16x32_bf16(                          \
            __builtin_bit_cast(bf16x8, hf),                                      \
            __builtin_bit_cast(bf16x8, w2f[kk]), acc2, 0, 0, 0);                 \
    }                                                                            \
    float* orow = out + (size_t)sdst * 264;                                      \
    _Pragma("unroll") for (int r = 0; r < 4; ++r) {                              \
        const int sl = __shfl(sslot, q * 4 + r);                                 \
        if (n < 8) orow[sl * 8 + n] = acc2[r] + b2v;                             \
    }                                                                            \
    if (done) break;                                                             \
    t = t1; t1 = t2;                                                             \
  }

__global__ __launch_bounds__(256, 4)
void edge_kernel(const u16* __restrict__ np, const u16* __restrict__ ap,
                 const float* __restrict__ W2, const float* __restrict__ b2,
                 const int* __restrict__ edge_src,
                 const int* __restrict__ edge_dst,
                 const int* __restrict__ edge_slot,
                 float* __restrict__ out, int n_tiles)
{
    const int wid = threadIdx.x >> 6;
    const int l   = threadIdx.x & 63;
    const int n   = l & 15;
    const int q   = l >> 4;

    // W2 B-fragments (N padded 8->16 with zeros): 16 VGPRs
    u32x4 w2f[4];
#pragma unroll
    for (int kk = 0; kk < 4; ++kk) {
        u32x4 w;
#pragma unroll
        for (int jp = 0; jp < 4; ++jp) {
            const int k = kk * 32 + q * 8 + jp * 2;
            const float f0 = (n < 8) ? W2[(size_t)k * 8 + n] : 0.f;
            const float f1 = (n < 8) ? W2[(size_t)(k + 1) * 8 + n] : 0.f;
            w[jp] = pk2(f0, f1);
        }
        w2f[kk] = w;
    }
    const float b2v = (n < 8) ? b2[n] : 0.f;

    const int stride = gridDim.x * 4;
    int t = blockIdx.x * 4 + wid;
    if (t >= n_tiles) return;

    // prologue: idx for t and t1, frags for t
    int src0 = 0, slot0 = 0;
    if (l < 16) { src0 = edge_src[t * 16 + l]; slot0 = edge_slot[t * 16 + l]; }
    int dst0 = edge_dst[t * 16];
    int t1 = (t + stride < n_tiles) ? t + stride : t;
    int src1 = 0, slot1 = 0;
    if (l < 16) { src1 = edge_src[t1 * 16 + l]; slot1 = edge_slot[t1 * 16 + l]; }
    int dst1 = edge_dst[t1 * 16];

    u32x4 np0[4], ap0[4], np1[4], ap1[4];
#pragma unroll
    for (int kk = 0; kk < 4; ++kk) {
        const int s = __shfl(src0, n);
        np0[kk] = *(const u32x4*)(np + (size_t)s * 128 + kk * 32 + q * 8);
    }
#pragma unroll
    for (int kk = 0; kk < 4; ++kk)
        ap0[kk] = *(const u32x4*)(ap + (size_t)dst0 * 128 + kk * 32 + q * 8);

    while (true) {
        EDGE_STEP(np0, ap0, src0, slot0, dst0, np1, ap1, src1, slot1, dst1)
        EDGE_STEP(np1, ap1, src1, slot1, dst1, np0, ap0, src0, slot0, dst0)
    }
}

extern "C" void kernel_launch(void* const* d_in, const int* in_sizes, int n_in,
                              void* d_out, int out_size, void* d_ws, size_t ws_size,
                              hipStream_t stream)
{
    const float* x_nbr   = (const float*)d_in[0];
    const float* x_agent = (const float*)d_in[1];
    const float* W1      = (const float*)d_in[2];
    const float* b1      = (const float*)d_in[3];
    const float* W2      = (const float*)d_in[4];
    const float* b2      = (const float*)d_in[5];
    const float* Wa      = (const float*)d_in[6];
    const float* ba      = (const float*)d_in[7];
    const int* edge_src  = (const int*)d_in[8];
    const int* edge_dst  = (const int*)d_in[9];
    const int* edge_slot = (const int*)d_in[10];

    const int E        = in_sizes[8];
    const int n_nodes  = in_sizes[0] / 128;
    const int n_agents = in_sizes[1] / 128;
    const int n_tiles  = E / 16;

    // ws: np (n_nodes*128 bf16 = 12.8 MB) | ap (n_agents*128 bf16 = 12.8 MB)
    u16* np = (u16*)d_ws;
    u16* ap = (u16*)d_ws + (size_t)n_nodes * 128;

    const int nbr_blocks = 256, agent_blocks = 256;
    precompute_kernel<<<dim3(nbr_blocks + agent_blocks), dim3(256), 0, stream>>>(
        x_nbr, x_agent, W1, b1, Wa, ba, np, ap, (float*)d_out,
        n_nodes, n_agents, nbr_blocks);
    edge_kernel<<<dim3(1024), dim3(256), 0, stream>>>(
        np, ap, W2, b2, edge_src, edge_dst, edge_slot, (float*)d_out, n_tiles);
}